// Round 1
// baseline (3568.953 us; speedup 1.0000x reference)
//
#include <hip/hip_runtime.h>
#include <hip/hip_bf16.h>
#include <math.h>

using bf16 = __hip_bfloat16;
typedef __attribute__((ext_vector_type(8))) short short8;   // 8 x bf16 (4 VGPR)
typedef __attribute__((ext_vector_type(4))) float f32x4;
typedef __attribute__((ext_vector_type(4))) unsigned int u32x4;

#define S_LEN 2048
#define HDIM  3584
#define NHEADS 16
#define NKVH   8
#define HD     256
#define IDIM   14336
#define QKV_LD 8192

// ---------- helpers ----------
__device__ __forceinline__ unsigned pk2bf(float a, float b) {
  // RTNE pack of two f32 -> two bf16 (low = a)
  unsigned ua = __float_as_uint(a), ub = __float_as_uint(b);
  ua += 0x7fffu + ((ua >> 16) & 1u);
  ub += 0x7fffu + ((ub >> 16) & 1u);
  return (ua >> 16) | (ub & 0xffff0000u);
}
__device__ __forceinline__ bf16 f2bf(float a) {
  unsigned ua = __float_as_uint(a);
  ua += 0x7fffu + ((ua >> 16) & 1u);
  unsigned short v = (unsigned short)(ua >> 16);
  return __builtin_bit_cast(__hip_bfloat16, v);
}
__device__ __forceinline__ float tanh_fast(float x) {
  x = fminf(fmaxf(x, -20.f), 20.f);
  float e = __expf(2.f * x);
  return (e - 1.f) / (e + 1.f);
}
__device__ __forceinline__ void gl_lds16(const void* g, void* l) {
  __builtin_amdgcn_global_load_lds((const __attribute__((address_space(1))) unsigned int*)g,
                                   (__attribute__((address_space(3))) unsigned int*)l,
                                   16, 0, 0);
}
__device__ __forceinline__ float block_reduce_sum(float v) {
  __shared__ float red[4];
  int lane = threadIdx.x & 63, w = threadIdx.x >> 6;
#pragma unroll
  for (int m = 1; m < 64; m <<= 1) v += __shfl_xor(v, m);
  __syncthreads();
  if (lane == 0) red[w] = v;
  __syncthreads();
  return red[0] + red[1] + red[2] + red[3];
}

// ---------- GEMM: C[M,N] = A_bf16[M,K] @ B_f32[K,N], 128x128x32 tiles ----------
#define EPI_BF16 0
#define EPI_F32  1
#define EPI_GELU 2

template<int EPI>
__global__ __launch_bounds__(256, 2) void gemm_kernel(
    const bf16* __restrict__ A, const float* __restrict__ B,
    void* __restrict__ C, const bf16* __restrict__ gate,
    int M, int N, int K, int ldb, int ldc)
{
  __shared__ char lds[16384];       // A: [0,8192) [m][k] 128x32 bf16; B^T: [8192,16384) [n][k] 128x32 bf16
  char* ldsA = lds;
  char* ldsB = lds + 8192;

  const int tid = threadIdx.x;
  const int w = tid >> 6, lane = tid & 63;
  const int ln = lane & 15, qd = lane >> 4;
  const int mq = w >> 1, nq = w & 1;

  const int mtiles = M >> 7;
  const int mt = blockIdx.x % mtiles, nt = blockIdx.x / mtiles;
  const int m0 = mt << 7, n0 = nt << 7;

  // A staging (global_load_lds, wave-uniform LDS base + lane*16)
  const bf16* agp  = A + (size_t)(m0 + w * 32 + (lane >> 2)) * K + (lane & 3) * 8;
  const bf16* agp2 = agp + (size_t)16 * K;
  char* ldsA_w = ldsA + w * 2048;

  // B staging: lane covers cols n0 + w*16 + (lane>>2) and +64; k rows (lane&3)*8 + i
  const unsigned lane_off = (unsigned)(((lane & 3) * 8) * ldb + n0 + w * 16 + (lane >> 2));
  const float* bk = B;
  char* ldsB_w = ldsB + (w * 16 + (lane >> 2)) * 64 + (lane & 3) * 16;

  f32x4 acc[4][4] = {};
  float fa[8], fb[8];
#pragma unroll
  for (int i = 0; i < 8; ++i) {
    fa[i] = bk[lane_off + (unsigned)(i * ldb)];
    fb[i] = bk[lane_off + (unsigned)(i * ldb) + 64u];
  }
  bk += (size_t)32 * ldb;

  for (int k0 = 0; k0 < K; k0 += 32) {
    __syncthreads();
    // write staged B (bf16) to LDS, transposed layout [n][k]
    u32x4 va = { pk2bf(fa[0], fa[1]), pk2bf(fa[2], fa[3]), pk2bf(fa[4], fa[5]), pk2bf(fa[6], fa[7]) };
    u32x4 vb = { pk2bf(fb[0], fb[1]), pk2bf(fb[2], fb[3]), pk2bf(fb[4], fb[5]), pk2bf(fb[6], fb[7]) };
    *(u32x4*)ldsB_w = va;
    *(u32x4*)(ldsB_w + 4096) = vb;
    // A tile: async global->LDS
    gl_lds16(agp,  ldsA_w);
    gl_lds16(agp2, ldsA_w + 1024);
    agp += 32; agp2 += 32;
    __syncthreads();
    // prefetch next B slice (overlaps MFMA)
    if (k0 + 32 < K) {
#pragma unroll
      for (int i = 0; i < 8; ++i) {
        fa[i] = bk[lane_off + (unsigned)(i * ldb)];
        fb[i] = bk[lane_off + (unsigned)(i * ldb) + 64u];
      }
      bk += (size_t)32 * ldb;
    }
    short8 af[4], bfr[4];
#pragma unroll
    for (int i = 0; i < 4; ++i)
      af[i] = *(const short8*)(ldsA + (mq * 64 + i * 16 + ln) * 64 + qd * 16);
#pragma unroll
    for (int j = 0; j < 4; ++j)
      bfr[j] = *(const short8*)(ldsB + (nq * 64 + j * 16 + ln) * 64 + qd * 16);
#pragma unroll
    for (int i = 0; i < 4; ++i)
#pragma unroll
      for (int j = 0; j < 4; ++j)
        acc[i][j] = __builtin_amdgcn_mfma_f32_16x16x32_bf16(af[i], bfr[j], acc[i][j], 0, 0, 0);
  }

  // epilogue
#pragma unroll
  for (int i = 0; i < 4; ++i) {
#pragma unroll
    for (int j = 0; j < 4; ++j) {
      const int mbase = m0 + mq * 64 + i * 16 + qd * 4;
      const int n = n0 + nq * 64 + j * 16 + ln;
#pragma unroll
      for (int r = 0; r < 4; ++r) {
        float v = acc[i][j][r];
        size_t off = (size_t)(mbase + r) * ldc + n;
        if (EPI == EPI_F32) {
          ((float*)C)[off] = v;
        } else if (EPI == EPI_BF16) {
          ((bf16*)C)[off] = f2bf(v);
        } else {
          float g = __bfloat162float(gate[off]);
          float t = tanh_fast(0.7978845608028654f * (g + 0.044715f * g * g * g));
          ((bf16*)C)[off] = f2bf(0.5f * g * (1.f + t) * v);
        }
      }
    }
  }
}

// ---------- RMSNorm: out_bf16 = x * rsqrt(mean(x^2)+eps) * w ----------
__global__ __launch_bounds__(256) void rmsnorm_kernel(
    const float* __restrict__ x, const float* __restrict__ wgt, bf16* __restrict__ out)
{
  const int row = blockIdx.x, tid = threadIdx.x;
  const float* xr = x + (size_t)row * HDIM;
  float v[14]; float ss = 0.f;
#pragma unroll
  for (int i = 0; i < 14; ++i) { v[i] = xr[tid + i * 256]; ss += v[i] * v[i]; }
  ss = block_reduce_sum(ss);
  float inv = rsqrtf(ss * (1.f / HDIM) + 1e-6f);
  bf16* orow = out + (size_t)row * HDIM;
#pragma unroll
  for (int i = 0; i < 14; ++i) orow[tid + i * 256] = f2bf(v[i] * inv * wgt[tid + i * 256]);
}

// ---------- residual join: x2 = x + rmsnorm(y,w1); optional h2 = rmsnorm_bf16(x2,w2) ----------
__device__ __forceinline__ float tofl(float v) { return v; }
__device__ __forceinline__ float tofl(bf16 v) { return __bfloat162float(v); }

template<int SECOND, typename YT>
__global__ __launch_bounds__(256) void join_kernel(
    const float* __restrict__ x, const YT* __restrict__ y,
    const float* __restrict__ w1, const float* __restrict__ w2,
    float* __restrict__ xout, bf16* __restrict__ h2out)
{
  const int row = blockIdx.x, tid = threadIdx.x;
  const float* xr = x + (size_t)row * HDIM;
  const YT* yr = y + (size_t)row * HDIM;
  float yv[14]; float ss = 0.f;
#pragma unroll
  for (int i = 0; i < 14; ++i) { float t = tofl(yr[tid + i * 256]); yv[i] = t; ss += t * t; }
  ss = block_reduce_sum(ss);
  float inv = rsqrtf(ss * (1.f / HDIM) + 1e-6f);
  float x2[14]; float ss2 = 0.f;
  float* xo = xout + (size_t)row * HDIM;
#pragma unroll
  for (int i = 0; i < 14; ++i) {
    float t = xr[tid + i * 256] + yv[i] * inv * w1[tid + i * 256];
    x2[i] = t; ss2 += t * t;
    xo[tid + i * 256] = t;
  }
  if (SECOND) {
    ss2 = block_reduce_sum(ss2);
    float inv2 = rsqrtf(ss2 * (1.f / HDIM) + 1e-6f);
    bf16* ho = h2out + (size_t)row * HDIM;
#pragma unroll
    for (int i = 0; i < 14; ++i) ho[tid + i * 256] = f2bf(x2[i] * inv2 * w2[tid + i * 256]);
  }
}

// ---------- RoPE on q (16 heads) and k (8 heads) in qkv buffer ----------
__global__ __launch_bounds__(256) void rope_kernel(bf16* __restrict__ qkv, const int* __restrict__ pos)
{
  int idx = blockIdx.x * 256 + threadIdx.x;     // 2048*24*128 threads
  int d = idx & 127;
  int head = (idx >> 7) % 24;
  int s = idx / (24 * 128);
  float inv = __expf(-(float)d * (9.210340371976184f / 128.f));  // 10000^(-d/128)
  float ang = (float)pos[s] * inv;
  float c = cosf(ang), sn = sinf(ang);
  size_t base = (size_t)s * QKV_LD + head * 256 + d;
  float x1 = __bfloat162float(qkv[base]);
  float x2 = __bfloat162float(qkv[base + 128]);
  qkv[base]       = f2bf(x1 * c - x2 * sn);
  qkv[base + 128] = f2bf(x2 * c + x1 * sn);
}

// ---------- transpose V: vT[c][s] = qkv[s][6144+c], c in [0,2048) ----------
__global__ __launch_bounds__(256) void vtrans_kernel(const bf16* __restrict__ qkv, bf16* __restrict__ vT)
{
  __shared__ bf16 t[64][72];
  const int tid = threadIdx.x;
  const int sb = blockIdx.x & 31, cb = blockIdx.x >> 5;
  const int s0 = sb << 6, c0 = cb << 6;
#pragma unroll
  for (int i = 0; i < 2; ++i) {
    int r = (tid >> 3) + i * 32;
    int c = (tid & 7) * 8;
    *(short8*)(&t[r][c]) = *(const short8*)(qkv + (size_t)(s0 + r) * QKV_LD + 6144 + c0 + c);
  }
  __syncthreads();
#pragma unroll
  for (int i = 0; i < 2; ++i) {
    int c = (tid >> 3) + i * 32;
    int r8 = (tid & 7) * 8;
    unsigned pk[4];
#pragma unroll
    for (int j = 0; j < 4; ++j) {
      unsigned lo = *(const unsigned short*)&t[r8 + 2 * j][c];
      unsigned hi = *(const unsigned short*)&t[r8 + 2 * j + 1][c];
      pk[j] = lo | (hi << 16);
    }
    u32x4 pv = { pk[0], pk[1], pk[2], pk[3] };
    *(u32x4*)(vT + (size_t)(c0 + c) * S_LEN + s0 + r8) = pv;
  }
}

// ---------- attention: flash-style, softcap => no online max needed ----------
__global__ __launch_bounds__(256, 2) void attn_kernel(
    const bf16* __restrict__ qkv, const bf16* __restrict__ vT, bf16* __restrict__ out)
{
  __shared__ bf16 Kl[64 * 264];     // [key][d], row stride 264 elems (pad 8)
  __shared__ bf16 Pl[4][16 * 72];   // per-wave P [m][k], row stride 72 elems

  const int tid = threadIdx.x, w = tid >> 6, lane = tid & 63;
  const int ln = lane & 15, qd = lane >> 4;
  const int h  = blockIdx.x >> 5;
  const int qt = blockIdx.x & 31;
  const int q0 = qt << 6;
  const int kvh = h >> 1;

  const int qrow = q0 + w * 16 + ln;
  short8 qf[8];
#pragma unroll
  for (int c = 0; c < 8; ++c)
    qf[c] = *(const short8*)(qkv + (size_t)qrow * QKV_LD + h * HD + c * 32 + qd * 8);

  f32x4 oacc[16] = {};
  float lsum[4] = {0.f, 0.f, 0.f, 0.f};

  const bf16* kbase = qkv + 4096 + kvh * HD;
  const bf16* vtb = vT + (size_t)(kvh * HD) * S_LEN;

  const int nkt = qt + 1;
  for (int kt = 0; kt < nkt; ++kt) {
    const int key0 = kt << 6;
    __syncthreads();
    {  // stage K tile
      const int r = tid >> 2;
      const bf16* krow = kbase + (size_t)(key0 + r) * QKV_LD;
      bf16* lrow = Kl + r * 264;
#pragma unroll
      for (int i = 0; i < 8; ++i) {
        int c = (tid & 3) + i * 4;
        *(short8*)(lrow + c * 8) = *(const short8*)(krow + c * 8);
      }
    }
    __syncthreads();
    // S = Q K^T
    f32x4 sacc[4] = {};
#pragma unroll
    for (int c = 0; c < 8; ++c) {
#pragma unroll
      for (int j = 0; j < 4; ++j) {
        short8 kf = *(const short8*)(Kl + (j * 16 + ln) * 264 + c * 32 + qd * 8);
        sacc[j] = __builtin_amdgcn_mfma_f32_16x16x32_bf16(qf[c], kf, sacc[j], 0, 0, 0);
      }
    }
    // softcap + exp + causal mask; write P (bf16) to wave-private LDS
    bf16* pw = Pl[w];
#pragma unroll
    for (int j = 0; j < 4; ++j) {
#pragma unroll
      for (int r = 0; r < 4; ++r) {
        int key = key0 + j * 16 + ln;
        int qg  = q0 + w * 16 + qd * 4 + r;
        float s = sacc[j][r] * 0.00125f;          // SCALE/SOFTCAP = 0.0625/50
        float lg = 50.f * tanh_fast(s);
        float e = (key <= qg) ? __expf(lg) : 0.f;
        lsum[r] += e;
        pw[(qd * 4 + r) * 72 + j * 16 + ln] = f2bf(e);
      }
    }
    // O += P @ V   (V-frags direct from vT global, L2/L3-resident)
#pragma unroll
    for (int c2 = 0; c2 < 2; ++c2) {
      short8 pf = *(const short8*)(pw + ln * 72 + c2 * 32 + qd * 8);
#pragma unroll
      for (int jd = 0; jd < 16; ++jd) {
        short8 vf = *(const short8*)(vtb + (size_t)(jd * 16 + ln) * S_LEN + key0 + c2 * 32 + qd * 8);
        oacc[jd] = __builtin_amdgcn_mfma_f32_16x16x32_bf16(pf, vf, oacc[jd], 0, 0, 0);
      }
    }
  }
  // row-sum reduce across the 16 column-lanes, then normalize + store
#pragma unroll
  for (int r = 0; r < 4; ++r) {
    float v = lsum[r];
    v += __shfl_xor(v, 1); v += __shfl_xor(v, 2); v += __shfl_xor(v, 4); v += __shfl_xor(v, 8);
    lsum[r] = 1.f / v;
  }
#pragma unroll
  for (int jd = 0; jd < 16; ++jd) {
#pragma unroll
    for (int r = 0; r < 4; ++r) {
      int srow = q0 + w * 16 + qd * 4 + r;
      int col = h * HD + jd * 16 + ln;
      out[(size_t)srow * (NHEADS * HD) + col] = f2bf(oacc[jd][r] * lsum[r]);
    }
  }
}

// ---------- launch ----------
extern "C" void kernel_launch(void* const* d_in, const int* in_sizes, int n_in,
                              void* d_out, int out_size, void* d_ws, size_t ws_size,
                              hipStream_t stream)
{
  const float* x    = (const float*)d_in[0];
  const int*   pos  = (const int*)d_in[1];
  const float* w_in = (const float*)d_in[3];
  const float* w_pa = (const float*)d_in[4];
  const float* w_pf = (const float*)d_in[5];
  const float* w_ff = (const float*)d_in[6];
  const float* wq   = (const float*)d_in[7];
  const float* wk   = (const float*)d_in[8];
  const float* wv   = (const float*)d_in[9];
  const float* wo   = (const float*)d_in[10];
  const float* wg   = (const float*)d_in[11];
  const float* wu   = (const float*)d_in[12];
  const float* wd   = (const float*)d_in[13];
  char* ws = (char*)d_ws;

  // workspace layout (224 MiB total), regions reused across disjoint lifetimes
  bf16*  qkv   = (bf16*)(ws + 0);            // 33,554,432  (later: h2 bf16)
  bf16*  hin   = (bf16*)(ws + 33554432);     // 16,777,216  (h_in; later attn bf16; later down bf16)
  bf16*  vTb   = (bf16*)(ws + 50331648);     //  8,388,608
  float* x2    = (float*)(ws + 58720256);    // 29,360,128
  float* proj  = (float*)(ws + 88080384);    // 29,360,128
  bf16*  gateb = (bf16*)(ws + 117440512);    // 58,720,256
  bf16*  actb  = (bf16*)(ws + 176160768);    // 58,720,256
  bf16*  attnb = hin;
  bf16*  downb = hin;
  bf16*  h2    = (bf16*)(ws + 0);

  rmsnorm_kernel<<<2048, 256, 0, stream>>>(x, w_in, hin);

  gemm_kernel<EPI_BF16><<<16 * 32, 256, 0, stream>>>(hin, wq, (void*)qkv,          nullptr, 2048, 4096, 3584, 4096, 8192);
  gemm_kernel<EPI_BF16><<<16 * 16, 256, 0, stream>>>(hin, wk, (void*)(qkv + 4096), nullptr, 2048, 2048, 3584, 2048, 8192);
  gemm_kernel<EPI_BF16><<<16 * 16, 256, 0, stream>>>(hin, wv, (void*)(qkv + 6144), nullptr, 2048, 2048, 3584, 2048, 8192);

  rope_kernel<<<(2048 * 24 * 128) / 256, 256, 0, stream>>>(qkv, pos);
  vtrans_kernel<<<32 * 32, 256, 0, stream>>>(qkv, vTb);
  attn_kernel<<<16 * 32, 256, 0, stream>>>(qkv, vTb, attnb);

  gemm_kernel<EPI_F32><<<16 * 28, 256, 0, stream>>>(attnb, wo, (void*)proj, nullptr, 2048, 3584, 4096, 3584, 3584);

  join_kernel<1, float><<<2048, 256, 0, stream>>>(x, proj, w_pa, w_pf, x2, h2);

  gemm_kernel<EPI_BF16><<<16 * 112, 256, 0, stream>>>(h2, wg, (void*)gateb, nullptr, 2048, 14336, 3584, 14336, 14336);
  gemm_kernel<EPI_GELU><<<16 * 112, 256, 0, stream>>>(h2, wu, (void*)actb,  gateb,   2048, 14336, 3584, 14336, 14336);
  gemm_kernel<EPI_BF16><<<16 * 28, 256, 0, stream>>>(actb, wd, (void*)downb, nullptr, 2048, 3584, 14336, 3584, 3584);

  join_kernel<0, bf16><<<2048, 256, 0, stream>>>(x2, downb, w_ff, nullptr, (float*)d_out, nullptr);
}